// Round 1
// baseline (296.493 us; speedup 1.0000x reference)
//
#include <hip/hip_runtime.h>
#include <math.h>

#define BN 512
#define ND 256
#define EH 128

// -------------------- Kernel A: LN + 4 projections --------------------
// grid 256 blocks, 4 rows each. ws outputs:
//   srcg [1024][128], tgtg [1024][128], apreg [1024][128] (=src@Ws^T+b1), tbg [1024][128] (=tgt@Wt^T)
__global__ __launch_bounds__(256) void prep_kernel(
    const float* __restrict__ latent,
    const float* __restrict__ sng, const float* __restrict__ snb,
    const float* __restrict__ tng, const float* __restrict__ tnb,
    const float* __restrict__ sW,  const float* __restrict__ sb,
    const float* __restrict__ tW,  const float* __restrict__ tbv,
    const float* __restrict__ W1,  const float* __restrict__ b1,
    float* __restrict__ srcg, float* __restrict__ tgtg,
    float* __restrict__ apreg, float* __restrict__ tbg)
{
  __shared__ float lns[4][256];
  __shared__ float lnt[4][256];
  __shared__ float ssrc[4][128];
  __shared__ float stgt[4][128];
  const int tid = threadIdx.x;
  const int w = tid >> 6, lane = tid & 63;
  const int row0 = blockIdx.x << 2;

  // phase 1: LN (one wave per row)
  {
    const int row = row0 + w;
    const float* x = latent + (size_t)row * ND;
    const int h = lane << 2;
    float4 xv = *(const float4*)(x + h);
    float s1 = xv.x + xv.y + xv.z + xv.w;
    float s2 = xv.x*xv.x + xv.y*xv.y + xv.z*xv.z + xv.w*xv.w;
    #pragma unroll
    for (int m = 1; m < 64; m <<= 1) {
      s1 += __shfl_xor(s1, m, 64);
      s2 += __shfl_xor(s2, m, 64);
    }
    const float mu  = s1 * (1.0f/256.0f);
    const float var = s2 * (1.0f/256.0f) - mu*mu;
    const float rstd = rsqrtf(var + 1e-5f);
    float4 ga = *(const float4*)(sng + h), ba = *(const float4*)(snb + h);
    float4 gb = *(const float4*)(tng + h), bb = *(const float4*)(tnb + h);
    const float n0 = (xv.x - mu)*rstd, n1 = (xv.y - mu)*rstd;
    const float n2 = (xv.z - mu)*rstd, n3 = (xv.w - mu)*rstd;
    lns[w][h+0] = n0*ga.x + ba.x; lns[w][h+1] = n1*ga.y + ba.y;
    lns[w][h+2] = n2*ga.z + ba.z; lns[w][h+3] = n3*ga.w + ba.w;
    lnt[w][h+0] = n0*gb.x + bb.x; lnt[w][h+1] = n1*gb.y + bb.y;
    lnt[w][h+2] = n2*gb.z + bb.z; lnt[w][h+3] = n3*gb.w + bb.w;
  }
  __syncthreads();

  const int side = tid >> 7, k = tid & 127;
  // phase 2: src = lns@sW^T+sb ; tgt = lnt@tW^T+tb
  {
    const float* W = side ? tW : sW;
    const float bias = side ? tbv[k] : sb[k];
    const float (*L)[256] = side ? lnt : lns;
    float a0 = bias, a1 = bias, a2 = bias, a3 = bias;
    const float* wr = W + (size_t)k * ND;
    for (int h4 = 0; h4 < ND; h4 += 4) {
      float4 wv = *(const float4*)(wr + h4);
      float4 l0 = *(const float4*)&L[0][h4];
      float4 l1 = *(const float4*)&L[1][h4];
      float4 l2 = *(const float4*)&L[2][h4];
      float4 l3 = *(const float4*)&L[3][h4];
      a0 += wv.x*l0.x + wv.y*l0.y + wv.z*l0.z + wv.w*l0.w;
      a1 += wv.x*l1.x + wv.y*l1.y + wv.z*l1.z + wv.w*l1.w;
      a2 += wv.x*l2.x + wv.y*l2.y + wv.z*l2.z + wv.w*l2.w;
      a3 += wv.x*l3.x + wv.y*l3.y + wv.z*l3.z + wv.w*l3.w;
    }
    if (!side) {
      ssrc[0][k]=a0; ssrc[1][k]=a1; ssrc[2][k]=a2; ssrc[3][k]=a3;
      srcg[(size_t)(row0+0)*EH+k]=a0; srcg[(size_t)(row0+1)*EH+k]=a1;
      srcg[(size_t)(row0+2)*EH+k]=a2; srcg[(size_t)(row0+3)*EH+k]=a3;
    } else {
      stgt[0][k]=a0; stgt[1][k]=a1; stgt[2][k]=a2; stgt[3][k]=a3;
      tgtg[(size_t)(row0+0)*EH+k]=a0; tgtg[(size_t)(row0+1)*EH+k]=a1;
      tgtg[(size_t)(row0+2)*EH+k]=a2; tgtg[(size_t)(row0+3)*EH+k]=a3;
    }
  }
  __syncthreads();

  // phase 3: Apre = src@Ws^T + b1 ; TB = tgt@Wt^T   (Ws=W1[:,:128], Wt=W1[:,128:256])
  {
    if (!side) {
      const float bb = b1[k];
      float a0=bb, a1=bb, a2=bb, a3=bb;
      const float* wr = W1 + (size_t)k * 384;
      for (int h4 = 0; h4 < EH; h4 += 4) {
        float4 wv = *(const float4*)(wr + h4);
        float4 l0 = *(const float4*)&ssrc[0][h4];
        float4 l1 = *(const float4*)&ssrc[1][h4];
        float4 l2 = *(const float4*)&ssrc[2][h4];
        float4 l3 = *(const float4*)&ssrc[3][h4];
        a0 += wv.x*l0.x + wv.y*l0.y + wv.z*l0.z + wv.w*l0.w;
        a1 += wv.x*l1.x + wv.y*l1.y + wv.z*l1.z + wv.w*l1.w;
        a2 += wv.x*l2.x + wv.y*l2.y + wv.z*l2.z + wv.w*l2.w;
        a3 += wv.x*l3.x + wv.y*l3.y + wv.z*l3.z + wv.w*l3.w;
      }
      apreg[(size_t)(row0+0)*EH+k]=a0; apreg[(size_t)(row0+1)*EH+k]=a1;
      apreg[(size_t)(row0+2)*EH+k]=a2; apreg[(size_t)(row0+3)*EH+k]=a3;
    } else {
      float a0=0.f, a1=0.f, a2=0.f, a3=0.f;
      const float* wr = W1 + (size_t)k * 384 + EH;
      for (int h4 = 0; h4 < EH; h4 += 4) {
        float4 wv = *(const float4*)(wr + h4);
        float4 l0 = *(const float4*)&stgt[0][h4];
        float4 l1 = *(const float4*)&stgt[1][h4];
        float4 l2 = *(const float4*)&stgt[2][h4];
        float4 l3 = *(const float4*)&stgt[3][h4];
        a0 += wv.x*l0.x + wv.y*l0.y + wv.z*l0.z + wv.w*l0.w;
        a1 += wv.x*l1.x + wv.y*l1.y + wv.z*l1.z + wv.w*l1.w;
        a2 += wv.x*l2.x + wv.y*l2.y + wv.z*l2.z + wv.w*l2.w;
        a3 += wv.x*l3.x + wv.y*l3.y + wv.z*l3.z + wv.w*l3.w;
      }
      tbg[(size_t)(row0+0)*EH+k]=a0; tbg[(size_t)(row0+1)*EH+k]=a1;
      tbg[(size_t)(row0+2)*EH+k]=a2; tbg[(size_t)(row0+3)*EH+k]=a3;
    }
  }
}

// -------------------- Kernel B: per-(b,i) edge row --------------------
// grid 1024 = (b,i). 256 thr = 16 kg x 16 jg, 8x8 register tile.
// wps[h][k] = src_i[h] * Wp[k][h]  (src folded in; k bank-swizzled)
// tgtT[h][j] = tgt[b][jt+j][h]
// P = tgtT^T @ wps ; hv = P + Apre[k] + TB[j][k]; gelu; dot W2; softsign.
__global__ __launch_bounds__(256, 3) void edge_kernel(
    const float* __restrict__ srcg, const float* __restrict__ tgtg,
    const float* __restrict__ apreg, const float* __restrict__ tbg,
    const float* __restrict__ W1, const float* __restrict__ W2,
    const float* __restrict__ b2, float* __restrict__ out)
{
  __shared__ float tgtT[32][132];   // h-chunk x j-tile(128)+pad
  __shared__ float wps[32][140];    // h-chunk x swizzled k (max idx 139)
  __shared__ float s_src[128];
  __shared__ float s_apre[128];
  __shared__ float s_w2[128];
  __shared__ float part[128][17];   // j x kg partial sums

  const int tid = threadIdx.x;
  const int blk = blockIdx.x;
  const int b = blk >> 9, i = blk & 511;
  const float b2s = b2[0];

  if (tid < 128) {
    s_src[tid]  = srcg[(size_t)blk * EH + tid];
    s_apre[tid] = apreg[(size_t)blk * EH + tid];
    s_w2[tid]   = W2[tid];
  }

  const int kg = tid & 15, jg = tid >> 4;
  const int k0 = kg << 3, j0 = jg << 3;
  const int p0 = k0 + ((k0 >> 5) << 2);          // swizzled base for this thread's k-octet
  const int sk = tid & 127;                      // staging k / j
  const int hh = (tid >> 7) << 4;                // 0 or 16
  const int pkk = sk + ((sk >> 5) << 2);

  const float* tgt_b = tgtg + (size_t)b * BN * EH;
  const float* tb_b  = tbg  + (size_t)b * BN * EH;
  float* orow = out + (size_t)(b * BN + i) * BN;

  __syncthreads();   // s_src ready before first wps staging

  for (int jt = 0; jt < BN; jt += 128) {
    float acc[8][8];
    #pragma unroll
    for (int jj = 0; jj < 8; ++jj)
      #pragma unroll
      for (int kk = 0; kk < 8; ++kk) acc[jj][kk] = 0.0f;

    for (int hc = 0; hc < 4; ++hc) {
      __syncthreads();   // previous chunk's compute done with buffers
      // stage tgtT chunk: 128 j x 32 h
      {
        const float* trow = tgt_b + (size_t)(jt + sk) * EH + hc * 32 + hh;
        #pragma unroll
        for (int h4 = 0; h4 < 16; h4 += 4) {
          float4 tv = *(const float4*)(trow + h4);
          tgtT[hh + h4 + 0][sk] = tv.x;
          tgtT[hh + h4 + 1][sk] = tv.y;
          tgtT[hh + h4 + 2][sk] = tv.z;
          tgtT[hh + h4 + 3][sk] = tv.w;
        }
        // stage wps chunk (src folded)
        const float* wrow = W1 + (size_t)sk * 384 + 256 + hc * 32 + hh;
        #pragma unroll
        for (int h4 = 0; h4 < 16; h4 += 4) {
          float4 wv = *(const float4*)(wrow + h4);
          const int hb = hc * 32 + hh + h4;
          wps[hh + h4 + 0][pkk] = wv.x * s_src[hb + 0];
          wps[hh + h4 + 1][pkk] = wv.y * s_src[hb + 1];
          wps[hh + h4 + 2][pkk] = wv.z * s_src[hb + 2];
          wps[hh + h4 + 3][pkk] = wv.w * s_src[hb + 3];
        }
      }
      __syncthreads();
      // compute: 32 h-steps, 8x8 FMA tile each
      #pragma unroll 4
      for (int h = 0; h < 32; ++h) {
        float4 xa = *(const float4*)&tgtT[h][j0];
        float4 xb = *(const float4*)&tgtT[h][j0 + 4];
        float4 wa = *(const float4*)&wps[h][p0];
        float4 wb = *(const float4*)&wps[h][p0 + 4];
        float xs[8] = {xa.x, xa.y, xa.z, xa.w, xb.x, xb.y, xb.z, xb.w};
        float wv[8] = {wa.x, wa.y, wa.z, wa.w, wb.x, wb.y, wb.z, wb.w};
        #pragma unroll
        for (int jj = 0; jj < 8; ++jj)
          #pragma unroll
          for (int kk = 0; kk < 8; ++kk)
            acc[jj][kk] = fmaf(xs[jj], wv[kk], acc[jj][kk]);
      }
    }

    // epilogue: gelu + W2 reduction over this thread's 8 k
    float4 ap0 = *(const float4*)&s_apre[k0];
    float4 ap1 = *(const float4*)&s_apre[k0 + 4];
    float4 w20 = *(const float4*)&s_w2[k0];
    float4 w21 = *(const float4*)&s_w2[k0 + 4];
    const float apv[8] = {ap0.x, ap0.y, ap0.z, ap0.w, ap1.x, ap1.y, ap1.z, ap1.w};
    const float w2v[8] = {w20.x, w20.y, w20.z, w20.w, w21.x, w21.y, w21.z, w21.w};
    #pragma unroll
    for (int jj = 0; jj < 8; ++jj) {
      const float* trow = tb_b + (size_t)(jt + j0 + jj) * EH + k0;
      float4 t0 = *(const float4*)(trow);
      float4 t1 = *(const float4*)(trow + 4);
      const float tv[8] = {t0.x, t0.y, t0.z, t0.w, t1.x, t1.y, t1.z, t1.w};
      float ps = 0.0f;
      #pragma unroll
      for (int kk = 0; kk < 8; ++kk) {
        const float hv = acc[jj][kk] + apv[kk] + tv[kk];
        const float g = 0.5f * hv * (1.0f + erff(hv * 0.70710678118654752f));
        ps = fmaf(w2v[kk], g, ps);
      }
      part[j0 + jj][kg] = ps;
    }
    __syncthreads();
    if (tid < 128) {
      const int j = tid;
      float s = b2s;
      #pragma unroll
      for (int c = 0; c < 16; ++c) s += part[j][c];
      const float e = s / (1.0f + fabsf(s));
      const int jG = jt + j;
      orow[jG] = (jG == i) ? 0.0f : e;
    }
    // next iteration's first __syncthreads() protects buffer reuse
  }
}

// -------------------- launch --------------------
extern "C" void kernel_launch(void* const* d_in, const int* in_sizes, int n_in,
                              void* d_out, int out_size, void* d_ws, size_t ws_size,
                              hipStream_t stream) {
  const float* latent = (const float*)d_in[0];
  const float* sng = (const float*)d_in[1];
  const float* snb = (const float*)d_in[2];
  const float* tng = (const float*)d_in[3];
  const float* tnb = (const float*)d_in[4];
  const float* sW  = (const float*)d_in[5];
  const float* sb  = (const float*)d_in[6];
  const float* tW  = (const float*)d_in[7];
  const float* tb  = (const float*)d_in[8];
  const float* W1  = (const float*)d_in[9];
  const float* b1  = (const float*)d_in[10];
  const float* W2  = (const float*)d_in[11];
  const float* b2  = (const float*)d_in[12];
  float* out = (float*)d_out;

  float* ws = (float*)d_ws;
  float* srcg  = ws;                 // [1024][128]
  float* tgtg  = ws + 131072;        // [1024][128]
  float* apreg = ws + 262144;        // [1024][128]
  float* tbg   = ws + 393216;        // [1024][128]

  hipLaunchKernelGGL(prep_kernel, dim3(256), dim3(256), 0, stream,
                     latent, sng, snb, tng, tnb, sW, sb, tW, tb, W1, b1,
                     srcg, tgtg, apreg, tbg);
  hipLaunchKernelGGL(edge_kernel, dim3(1024), dim3(256), 0, stream,
                     srcg, tgtg, apreg, tbg, W1, W2, b2, out);
}

// Round 2
// 188.969 us; speedup vs baseline: 1.5690x; 1.5690x over previous
//
#include <hip/hip_runtime.h>
#include <math.h>

#define BN 512
#define ND 256
#define EH 128

typedef __attribute__((ext_vector_type(8))) short short8v;
typedef __attribute__((ext_vector_type(4))) float f32x4;

__device__ __forceinline__ unsigned short f2bf_rn(float x) {
  unsigned int u = __float_as_uint(x);
  unsigned int r = u + 0x7FFFu + ((u >> 16) & 1u);
  return (unsigned short)(r >> 16);
}
__device__ __forceinline__ float bf2f(unsigned short h) {
  return __uint_as_float(((unsigned int)h) << 16);
}

// -------------------- Kernel A: LN + projections + tgt bf16 split --------------------
// grid 256 blocks x 256 thr, 4 rows each.
// ws: srcg f32[1024][128], apreg f32[1024][128] (=src@Ws^T+b1),
//     tgthi u16[1024][128], tgtlo u16[1024][128]
__global__ __launch_bounds__(256) void prep_kernel(
    const float* __restrict__ latent,
    const float* __restrict__ sng, const float* __restrict__ snb,
    const float* __restrict__ tng, const float* __restrict__ tnb,
    const float* __restrict__ sW,  const float* __restrict__ sb,
    const float* __restrict__ tW,  const float* __restrict__ tbv,
    const float* __restrict__ W1,  const float* __restrict__ b1,
    float* __restrict__ srcg, float* __restrict__ apreg,
    unsigned short* __restrict__ tgthi, unsigned short* __restrict__ tgtlo)
{
  __shared__ float lns[4][256];
  __shared__ float lnt[4][256];
  __shared__ float ssrc[4][128];
  const int tid = threadIdx.x;
  const int w = tid >> 6, lane = tid & 63;
  const int row0 = blockIdx.x << 2;

  // phase 1: LN (one wave per row)
  {
    const int row = row0 + w;
    const float* x = latent + (size_t)row * ND;
    const int h = lane << 2;
    float4 xv = *(const float4*)(x + h);
    float s1 = xv.x + xv.y + xv.z + xv.w;
    float s2 = xv.x*xv.x + xv.y*xv.y + xv.z*xv.z + xv.w*xv.w;
    #pragma unroll
    for (int m = 1; m < 64; m <<= 1) {
      s1 += __shfl_xor(s1, m, 64);
      s2 += __shfl_xor(s2, m, 64);
    }
    const float mu  = s1 * (1.0f/256.0f);
    const float var = s2 * (1.0f/256.0f) - mu*mu;
    const float rstd = rsqrtf(var + 1e-5f);
    float4 ga = *(const float4*)(sng + h), ba = *(const float4*)(snb + h);
    float4 gb = *(const float4*)(tng + h), bb = *(const float4*)(tnb + h);
    const float n0 = (xv.x - mu)*rstd, n1 = (xv.y - mu)*rstd;
    const float n2 = (xv.z - mu)*rstd, n3 = (xv.w - mu)*rstd;
    lns[w][h+0] = n0*ga.x + ba.x; lns[w][h+1] = n1*ga.y + ba.y;
    lns[w][h+2] = n2*ga.z + ba.z; lns[w][h+3] = n3*ga.w + ba.w;
    lnt[w][h+0] = n0*gb.x + bb.x; lnt[w][h+1] = n1*gb.y + bb.y;
    lnt[w][h+2] = n2*gb.z + bb.z; lnt[w][h+3] = n3*gb.w + bb.w;
  }
  __syncthreads();

  const int side = tid >> 7, k = tid & 127;
  // phase 2: src = lns@sW^T+sb (side 0) ; tgt = lnt@tW^T+tb (side 1, split to bf16)
  {
    const float* W = side ? tW : sW;
    const float bias = side ? tbv[k] : sb[k];
    const float (*L)[256] = side ? lnt : lns;
    float a0 = bias, a1 = bias, a2 = bias, a3 = bias;
    const float* wr = W + (size_t)k * ND;
    for (int h4 = 0; h4 < ND; h4 += 4) {
      float4 wv = *(const float4*)(wr + h4);
      float4 l0 = *(const float4*)&L[0][h4];
      float4 l1 = *(const float4*)&L[1][h4];
      float4 l2 = *(const float4*)&L[2][h4];
      float4 l3 = *(const float4*)&L[3][h4];
      a0 += wv.x*l0.x + wv.y*l0.y + wv.z*l0.z + wv.w*l0.w;
      a1 += wv.x*l1.x + wv.y*l1.y + wv.z*l1.z + wv.w*l1.w;
      a2 += wv.x*l2.x + wv.y*l2.y + wv.z*l2.z + wv.w*l2.w;
      a3 += wv.x*l3.x + wv.y*l3.y + wv.z*l3.z + wv.w*l3.w;
    }
    if (!side) {
      ssrc[0][k]=a0; ssrc[1][k]=a1; ssrc[2][k]=a2; ssrc[3][k]=a3;
      srcg[(size_t)(row0+0)*EH+k]=a0; srcg[(size_t)(row0+1)*EH+k]=a1;
      srcg[(size_t)(row0+2)*EH+k]=a2; srcg[(size_t)(row0+3)*EH+k]=a3;
    } else {
      float av[4] = {a0, a1, a2, a3};
      #pragma unroll
      for (int r = 0; r < 4; ++r) {
        unsigned short hi = f2bf_rn(av[r]);
        unsigned short lo = f2bf_rn(av[r] - bf2f(hi));
        tgthi[(size_t)(row0+r)*EH + k] = hi;
        tgtlo[(size_t)(row0+r)*EH + k] = lo;
      }
    }
  }
  __syncthreads();

  // phase 3: Apre = src@Ws^T + b1   (Ws = W1[:, :128]); all 256 threads, 2 rows each
  {
    const int kk = tid & 127, half = tid >> 7;
    const float bb = b1[kk];
    float a0 = bb, a1 = bb;
    const float* wr = W1 + (size_t)kk * 384;
    const int r0 = half * 2;
    for (int h4 = 0; h4 < EH; h4 += 4) {
      float4 wv = *(const float4*)(wr + h4);
      float4 l0 = *(const float4*)&ssrc[r0][h4];
      float4 l1 = *(const float4*)&ssrc[r0+1][h4];
      a0 += wv.x*l0.x + wv.y*l0.y + wv.z*l0.z + wv.w*l0.w;
      a1 += wv.x*l1.x + wv.y*l1.y + wv.z*l1.z + wv.w*l1.w;
    }
    apreg[(size_t)(row0+r0)*EH + kk]   = a0;
    apreg[(size_t)(row0+r0+1)*EH + kk] = a1;
  }
}

// -------------------- Kernel B: per-(b,i) MFMA edge row --------------------
// grid 1024 = (b,i), 256 thr = 4 waves.
// G'[k][h] = src_i[h]*Wp[k][h] + Wt[k][h], split bf16 hi/lo in swizzled LDS.
// h_val = tgt @ G'^T + Apre; gelu (A&S erf); logits = <W2, gelu>; softsign; diag=0.
__global__ __launch_bounds__(256, 2) void edge_kernel(
    const float* __restrict__ srcg, const float* __restrict__ apreg,
    const unsigned short* __restrict__ tgthi, const unsigned short* __restrict__ tgtlo,
    const float* __restrict__ W1, const float* __restrict__ W2,
    const float* __restrict__ b2, float* __restrict__ out)
{
  __shared__ __align__(16) unsigned short Ghi[128 * 128]; // [k][h] swizzled, 32KB
  __shared__ __align__(16) unsigned short Glo[128 * 128]; // 32KB
  __shared__ float s_src[128];

  const int tid = threadIdx.x;
  const int l = tid & 63, w = tid >> 6;
  const int blk = blockIdx.x;
  const int b = blk >> 9, i = blk & 511;

  if (tid < 128) s_src[tid] = srcg[(size_t)blk * EH + tid];
  __syncthreads();

  // ---- stage G' (hi/lo bf16, XOR-swizzled rows) ----
  {
    const int k = tid >> 1, h0 = (tid & 1) * 64;
    const float* wpr = W1 + (size_t)k * 384 + 256 + h0;
    const float* wtr = W1 + (size_t)k * 384 + 128 + h0;
    const unsigned int swz = (unsigned int)((k & 15) << 4);
    char* ghB = (char*)Ghi + k * 256;
    char* glB = (char*)Glo + k * 256;
    #pragma unroll
    for (int c = 0; c < 64; c += 8) {
      float4 wpa = *(const float4*)(wpr + c);
      float4 wpb = *(const float4*)(wpr + c + 4);
      float4 wta = *(const float4*)(wtr + c);
      float4 wtb = *(const float4*)(wtr + c + 4);
      float4 sa  = *(const float4*)&s_src[h0 + c];
      float4 sb4 = *(const float4*)&s_src[h0 + c + 4];
      float g[8];
      g[0] = fmaf(sa.x,  wpa.x, wta.x); g[1] = fmaf(sa.y,  wpa.y, wta.y);
      g[2] = fmaf(sa.z,  wpa.z, wta.z); g[3] = fmaf(sa.w,  wpa.w, wta.w);
      g[4] = fmaf(sb4.x, wpb.x, wtb.x); g[5] = fmaf(sb4.y, wpb.y, wtb.y);
      g[6] = fmaf(sb4.z, wpb.z, wtb.z); g[7] = fmaf(sb4.w, wpb.w, wtb.w);
      short8v hv, lv;
      #pragma unroll
      for (int q = 0; q < 8; ++q) {
        unsigned short hh = f2bf_rn(g[q]);
        hv[q] = (short)hh;
        lv[q] = (short)f2bf_rn(g[q] - bf2f(hh));
      }
      const unsigned int off = ((unsigned int)((h0 + c) * 2)) ^ swz;
      *(short8v*)(ghB + off) = hv;
      *(short8v*)(glB + off) = lv;
    }
  }
  __syncthreads();

  // per-lane epilogue constants: k-column = nt*16 + (l&15)
  const int l15 = l & 15;
  const int hi4 = l >> 4;           // 0..3
  float apv[8], w2h[8];
  #pragma unroll
  for (int nt = 0; nt < 8; ++nt) {
    apv[nt] = apreg[(size_t)blk * EH + nt * 16 + l15];
    w2h[nt] = 0.5f * W2[nt * 16 + l15];
  }
  const float b2s = b2[0];

  const unsigned short* thB = tgthi + (size_t)b * BN * EH;
  const unsigned short* tlB = tgtlo + (size_t)b * BN * EH;
  float* orow = out + (size_t)blk * BN;

  const int cb = hi4 * 16;          // byte col base within row for B frags
  const unsigned int swzl = (unsigned int)(l15 << 4);

  // 2 passes x 4 m-tiles (16 j each) per wave: wave w covers j-tiles w*8 .. w*8+7
  #pragma unroll 1
  for (int p = 0; p < 2; ++p) {
    const int jt0 = (w * 8 + p * 4) * 16;
    f32x4 acc[4][8];
    #pragma unroll
    for (int m = 0; m < 4; ++m)
      #pragma unroll
      for (int nt = 0; nt < 8; ++nt)
        acc[m][nt] = (f32x4){0.f, 0.f, 0.f, 0.f};

    #pragma unroll
    for (int ks = 0; ks < 4; ++ks) {
      short8v a_hi[4], a_lo[4];
      #pragma unroll
      for (int m = 0; m < 4; ++m) {
        const size_t r = (size_t)(jt0 + m * 16 + l15) * EH + ks * 32 + hi4 * 8;
        a_hi[m] = *(const short8v*)(thB + r);
        a_lo[m] = *(const short8v*)(tlB + r);
      }
      #pragma unroll
      for (int nt = 0; nt < 8; ++nt) {
        const int rowoff = nt * 4096 + l15 * 256;
        const unsigned int col = ((unsigned int)((ks << 6) | cb)) ^ swzl;
        short8v bhi = *(const short8v*)((const char*)Ghi + rowoff + col);
        short8v blo = *(const short8v*)((const char*)Glo + rowoff + col);
        #pragma unroll
        for (int m = 0; m < 4; ++m) {
          acc[m][nt] = __builtin_amdgcn_mfma_f32_16x16x32_bf16(a_hi[m], bhi, acc[m][nt], 0, 0, 0);
          acc[m][nt] = __builtin_amdgcn_mfma_f32_16x16x32_bf16(a_hi[m], blo, acc[m][nt], 0, 0, 0);
          acc[m][nt] = __builtin_amdgcn_mfma_f32_16x16x32_bf16(a_lo[m], bhi, acc[m][nt], 0, 0, 0);
        }
      }
    }

    // ---- epilogue: gelu + W2 dot + softsign ----
    #pragma unroll
    for (int m = 0; m < 4; ++m) {
      #pragma unroll
      for (int reg = 0; reg < 4; ++reg) {
        float ps = 0.0f;
        #pragma unroll
        for (int nt = 0; nt < 8; ++nt) {
          const float x = acc[m][nt][reg] + apv[nt];
          // exact-gelu via A&S 7.1.26 erf (abs err 2.5e-5)
          const float e  = __builtin_amdgcn_exp2f(x * x * -0.7213475204f); // exp(-x^2/2)
          const float t  = __builtin_amdgcn_rcpf(fmaf(0.33267817f, fabsf(x), 1.0f));
          const float pl = t * fmaf(t, fmaf(t, 0.7478556f, -0.0958798f), 0.3480242f);
          const float u  = x * (pl * e);            // x * (1-|erf|) term
          const float tw = fmaf(2.0f, x, -u);       // 2x - u
          const float g2 = (x < 0.0f) ? u : tw;     // = 2*gelu(x)
          ps = fmaf(w2h[nt], g2, ps);
        }
        ps += __shfl_xor(ps, 1, 64);
        ps += __shfl_xor(ps, 2, 64);
        ps += __shfl_xor(ps, 4, 64);
        ps += __shfl_xor(ps, 8, 64);
        if (l15 == 0) {
          const int j = jt0 + m * 16 + hi4 * 4 + reg;
          const float s = ps + b2s;
          const float e2 = s / (1.0f + fabsf(s));
          orow[j] = (j == i) ? 0.0f : e2;
        }
      }
    }
  }
}

// -------------------- launch --------------------
extern "C" void kernel_launch(void* const* d_in, const int* in_sizes, int n_in,
                              void* d_out, int out_size, void* d_ws, size_t ws_size,
                              hipStream_t stream) {
  const float* latent = (const float*)d_in[0];
  const float* sng = (const float*)d_in[1];
  const float* snb = (const float*)d_in[2];
  const float* tng = (const float*)d_in[3];
  const float* tnb = (const float*)d_in[4];
  const float* sW  = (const float*)d_in[5];
  const float* sb  = (const float*)d_in[6];
  const float* tW  = (const float*)d_in[7];
  const float* tb  = (const float*)d_in[8];
  const float* W1  = (const float*)d_in[9];
  const float* b1  = (const float*)d_in[10];
  const float* W2  = (const float*)d_in[11];
  const float* b2  = (const float*)d_in[12];
  float* out = (float*)d_out;

  float* ws = (float*)d_ws;
  float* srcg  = ws;                                   // [1024][128] f32
  float* apreg = ws + 131072;                          // [1024][128] f32
  unsigned short* tgthi = (unsigned short*)(ws + 262144); // [1024][128] u16
  unsigned short* tgtlo = (unsigned short*)(ws + 327680); // [1024][128] u16

  hipLaunchKernelGGL(prep_kernel, dim3(256), dim3(256), 0, stream,
                     latent, sng, snb, tng, tnb, sW, sb, tW, tb, W1, b1,
                     srcg, apreg, tgthi, tgtlo);
  hipLaunchKernelGGL(edge_kernel, dim3(1024), dim3(256), 0, stream,
                     srcg, apreg, tgthi, tgtlo, W1, W2, b2, out);
}

// Round 3
// 84.133 us; speedup vs baseline: 3.5241x; 2.2461x over previous
//
#include <hip/hip_runtime.h>
#include <math.h>

#define BN 512
#define ND 256
#define EH 128

typedef __attribute__((ext_vector_type(8))) short short8v;
typedef __attribute__((ext_vector_type(4))) float f32x4;

__device__ __forceinline__ unsigned short f2bf_rn(float x) {
  unsigned int u = __float_as_uint(x);
  unsigned int r = u + 0x7FFFu + ((u >> 16) & 1u);
  return (unsigned short)(r >> 16);
}
__device__ __forceinline__ float bf2f(unsigned short h) {
  return __uint_as_float(((unsigned int)h) << 16);
}

// -------------------- Kernel A: LN + projections + tgt bf16 --------------------
// grid 256 blocks x 256 thr, 4 rows each.
// ws: srcg f32[1024][128], apreg f32[1024][128] (=src@Ws^T+b1), tgtb u16[1024][128]
__global__ __launch_bounds__(256) void prep_kernel(
    const float* __restrict__ latent,
    const float* __restrict__ sng, const float* __restrict__ snb,
    const float* __restrict__ tng, const float* __restrict__ tnb,
    const float* __restrict__ sW,  const float* __restrict__ sb,
    const float* __restrict__ tW,  const float* __restrict__ tbv,
    const float* __restrict__ W1,  const float* __restrict__ b1,
    float* __restrict__ srcg, float* __restrict__ apreg,
    unsigned short* __restrict__ tgtb)
{
  __shared__ float lns[4][256];
  __shared__ float lnt[4][256];
  __shared__ float ssrc[4][128];
  const int tid = threadIdx.x;
  const int w = tid >> 6, lane = tid & 63;
  const int row0 = blockIdx.x << 2;

  // phase 1: LN (one wave per row)
  {
    const int row = row0 + w;
    const float* x = latent + (size_t)row * ND;
    const int h = lane << 2;
    float4 xv = *(const float4*)(x + h);
    float s1 = xv.x + xv.y + xv.z + xv.w;
    float s2 = xv.x*xv.x + xv.y*xv.y + xv.z*xv.z + xv.w*xv.w;
    #pragma unroll
    for (int m = 1; m < 64; m <<= 1) {
      s1 += __shfl_xor(s1, m, 64);
      s2 += __shfl_xor(s2, m, 64);
    }
    const float mu  = s1 * (1.0f/256.0f);
    const float var = s2 * (1.0f/256.0f) - mu*mu;
    const float rstd = rsqrtf(var + 1e-5f);
    float4 ga = *(const float4*)(sng + h), ba = *(const float4*)(snb + h);
    float4 gb = *(const float4*)(tng + h), bb = *(const float4*)(tnb + h);
    const float n0 = (xv.x - mu)*rstd, n1 = (xv.y - mu)*rstd;
    const float n2 = (xv.z - mu)*rstd, n3 = (xv.w - mu)*rstd;
    lns[w][h+0] = n0*ga.x + ba.x; lns[w][h+1] = n1*ga.y + ba.y;
    lns[w][h+2] = n2*ga.z + ba.z; lns[w][h+3] = n3*ga.w + ba.w;
    lnt[w][h+0] = n0*gb.x + bb.x; lnt[w][h+1] = n1*gb.y + bb.y;
    lnt[w][h+2] = n2*gb.z + bb.z; lnt[w][h+3] = n3*gb.w + bb.w;
  }
  __syncthreads();

  const int side = tid >> 7, k = tid & 127;
  // phase 2: src = lns@sW^T+sb (side 0, f32) ; tgt = lnt@tW^T+tb (side 1, bf16 rn)
  {
    const float* W = side ? tW : sW;
    const float bias = side ? tbv[k] : sb[k];
    const float (*L)[256] = side ? lnt : lns;
    float a0 = bias, a1 = bias, a2 = bias, a3 = bias;
    const float* wr = W + (size_t)k * ND;
    for (int h4 = 0; h4 < ND; h4 += 4) {
      float4 wv = *(const float4*)(wr + h4);
      float4 l0 = *(const float4*)&L[0][h4];
      float4 l1 = *(const float4*)&L[1][h4];
      float4 l2 = *(const float4*)&L[2][h4];
      float4 l3 = *(const float4*)&L[3][h4];
      a0 += wv.x*l0.x + wv.y*l0.y + wv.z*l0.z + wv.w*l0.w;
      a1 += wv.x*l1.x + wv.y*l1.y + wv.z*l1.z + wv.w*l1.w;
      a2 += wv.x*l2.x + wv.y*l2.y + wv.z*l2.z + wv.w*l2.w;
      a3 += wv.x*l3.x + wv.y*l3.y + wv.z*l3.z + wv.w*l3.w;
    }
    if (!side) {
      ssrc[0][k]=a0; ssrc[1][k]=a1; ssrc[2][k]=a2; ssrc[3][k]=a3;
      srcg[(size_t)(row0+0)*EH+k]=a0; srcg[(size_t)(row0+1)*EH+k]=a1;
      srcg[(size_t)(row0+2)*EH+k]=a2; srcg[(size_t)(row0+3)*EH+k]=a3;
    } else {
      tgtb[(size_t)(row0+0)*EH + k] = f2bf_rn(a0);
      tgtb[(size_t)(row0+1)*EH + k] = f2bf_rn(a1);
      tgtb[(size_t)(row0+2)*EH + k] = f2bf_rn(a2);
      tgtb[(size_t)(row0+3)*EH + k] = f2bf_rn(a3);
    }
  }
  __syncthreads();

  // phase 3: Apre = src@Ws^T + b1   (Ws = W1[:, :128]); 256 threads, 2 rows each
  {
    const int kk = tid & 127, half = tid >> 7;
    const float bb = b1[kk];
    float a0 = bb, a1 = bb;
    const float* wr = W1 + (size_t)kk * 384;
    const int r0 = half * 2;
    for (int h4 = 0; h4 < EH; h4 += 4) {
      float4 wv = *(const float4*)(wr + h4);
      float4 l0 = *(const float4*)&ssrc[r0][h4];
      float4 l1 = *(const float4*)&ssrc[r0+1][h4];
      a0 += wv.x*l0.x + wv.y*l0.y + wv.z*l0.z + wv.w*l0.w;
      a1 += wv.x*l1.x + wv.y*l1.y + wv.z*l1.z + wv.w*l1.w;
    }
    apreg[(size_t)(row0+r0)*EH + kk]   = a0;
    apreg[(size_t)(row0+r0+1)*EH + kk] = a1;
  }
}

// -------------------- Kernel B: per-(b,i) MFMA edge row --------------------
// grid 1024 = (b,i), 256 thr = 4 waves.
// G'[k][h] = src_i[h]*Wp[k][h] + Wt[k][h], split bf16 hi/lo in swizzled LDS.
// h_val = tgt @ G'^T + Apre; gelu (A&S erf); logits = <W2, gelu>; softsign; diag=0.
__global__ __launch_bounds__(256, 2) void edge_kernel(
    const float* __restrict__ srcg, const float* __restrict__ apreg,
    const unsigned short* __restrict__ tgtb,
    const float* __restrict__ W1, const float* __restrict__ W2,
    const float* __restrict__ b2, float* __restrict__ out)
{
  __shared__ __align__(16) unsigned short Ghi[128 * 128]; // [k][h] swizzled, 32KB
  __shared__ __align__(16) unsigned short Glo[128 * 128]; // 32KB
  __shared__ float s_src[128];

  const int tid = threadIdx.x;
  const int l = tid & 63, w = tid >> 6;
  const int blk = blockIdx.x;
  const int b = blk >> 9, i = blk & 511;

  if (tid < 128) s_src[tid] = srcg[(size_t)blk * EH + tid];
  __syncthreads();

  // ---- stage G' (hi/lo bf16, XOR-swizzled rows) ----
  {
    const int k = tid >> 1, h0 = (tid & 1) * 64;
    const float* wpr = W1 + (size_t)k * 384 + 256 + h0;
    const float* wtr = W1 + (size_t)k * 384 + 128 + h0;
    const unsigned int swz = (unsigned int)((k & 15) << 4);
    char* ghB = (char*)Ghi + k * 256;
    char* glB = (char*)Glo + k * 256;
    #pragma unroll
    for (int c = 0; c < 64; c += 8) {
      float4 wpa = *(const float4*)(wpr + c);
      float4 wpb = *(const float4*)(wpr + c + 4);
      float4 wta = *(const float4*)(wtr + c);
      float4 wtb = *(const float4*)(wtr + c + 4);
      float4 sa  = *(const float4*)&s_src[h0 + c];
      float4 sb4 = *(const float4*)&s_src[h0 + c + 4];
      float g[8];
      g[0] = fmaf(sa.x,  wpa.x, wta.x); g[1] = fmaf(sa.y,  wpa.y, wta.y);
      g[2] = fmaf(sa.z,  wpa.z, wta.z); g[3] = fmaf(sa.w,  wpa.w, wta.w);
      g[4] = fmaf(sb4.x, wpb.x, wtb.x); g[5] = fmaf(sb4.y, wpb.y, wtb.y);
      g[6] = fmaf(sb4.z, wpb.z, wtb.z); g[7] = fmaf(sb4.w, wpb.w, wtb.w);
      short8v hv, lv;
      #pragma unroll
      for (int q = 0; q < 8; ++q) {
        unsigned short hh = f2bf_rn(g[q]);
        hv[q] = (short)hh;
        lv[q] = (short)f2bf_rn(g[q] - bf2f(hh));
      }
      const unsigned int off = ((unsigned int)((h0 + c) * 2)) ^ swz;
      *(short8v*)(ghB + off) = hv;
      *(short8v*)(glB + off) = lv;
    }
  }
  __syncthreads();

  // per-lane epilogue constants: k-column = nt*16 + (l&15)
  const int l15 = l & 15;
  const int hi4 = l >> 4;           // 0..3
  float apv[8], w2h[8];
  #pragma unroll
  for (int nt = 0; nt < 8; ++nt) {
    apv[nt] = apreg[(size_t)blk * EH + nt * 16 + l15];
    w2h[nt] = 0.5f * W2[nt * 16 + l15];
  }
  const float b2s = b2[0];

  const unsigned short* tB = tgtb + (size_t)b * BN * EH;
  float* orow = out + (size_t)blk * BN;

  const int cb = hi4 * 16;          // byte col base within row for B frags
  const unsigned int swzl = (unsigned int)(l15 << 4);

#define LOADA(buf, ks_)                                                        \
  {                                                                            \
    _Pragma("unroll")                                                          \
    for (int m = 0; m < 4; ++m) {                                              \
      const size_t r = (size_t)(jt0 + m * 16 + l15) * EH + (ks_) * 32 + hi4 * 8;\
      buf[m] = *(const short8v*)(tB + r);                                      \
    }                                                                          \
  }

#define MFMA_STEP(buf, ks_)                                                    \
  {                                                                            \
    _Pragma("unroll")                                                          \
    for (int nt = 0; nt < 8; ++nt) {                                           \
      const int rowoff = nt * 4096 + l15 * 256;                                \
      const unsigned int col = ((unsigned int)(((ks_) << 6) | cb)) ^ swzl;     \
      short8v bhi = *(const short8v*)((const char*)Ghi + rowoff + col);        \
      short8v blo = *(const short8v*)((const char*)Glo + rowoff + col);        \
      _Pragma("unroll")                                                        \
      for (int m = 0; m < 4; ++m) {                                            \
        acc[m][nt] = __builtin_amdgcn_mfma_f32_16x16x32_bf16(buf[m], bhi, acc[m][nt], 0, 0, 0); \
        acc[m][nt] = __builtin_amdgcn_mfma_f32_16x16x32_bf16(buf[m], blo, acc[m][nt], 0, 0, 0); \
      }                                                                        \
    }                                                                          \
  }

  // 2 passes x 4 m-tiles (16 j each) per wave: wave w covers j-tiles w*8 .. w*8+7
  #pragma unroll 1
  for (int p = 0; p < 2; ++p) {
    const int jt0 = (w * 8 + p * 4) * 16;
    f32x4 acc[4][8];
    #pragma unroll
    for (int m = 0; m < 4; ++m)
      #pragma unroll
      for (int nt = 0; nt < 8; ++nt)
        acc[m][nt] = (f32x4){0.f, 0.f, 0.f, 0.f};

    // software-pipelined ks loop: 4 steps, 2-deep A prefetch, no big unroll
    short8v aA[4], aB[4];
    LOADA(aA, 0)
    #pragma unroll 1
    for (int kk = 0; kk < 2; ++kk) {
      const int ks0 = kk * 2;
      LOADA(aB, ks0 + 1)
      MFMA_STEP(aA, ks0)
      if (kk == 0) LOADA(aA, 2)
      MFMA_STEP(aB, ks0 + 1)
    }

    // ---- epilogue: gelu + W2 dot + softsign ----
    #pragma unroll
    for (int m = 0; m < 4; ++m) {
      #pragma unroll
      for (int reg = 0; reg < 4; ++reg) {
        float ps = 0.0f;
        #pragma unroll
        for (int nt = 0; nt < 8; ++nt) {
          const float x = acc[m][nt][reg] + apv[nt];
          // exact-gelu via A&S 7.1.26 erf (abs err 2.5e-5)
          const float e  = __builtin_amdgcn_exp2f(x * x * -0.7213475204f); // exp(-x^2/2)
          const float t  = __builtin_amdgcn_rcpf(fmaf(0.33267817f, fabsf(x), 1.0f));
          const float pl = t * fmaf(t, fmaf(t, 0.7478556f, -0.0958798f), 0.3480242f);
          const float u  = x * (pl * e);            // x * (1-|erf|) term
          const float tw = fmaf(2.0f, x, -u);       // 2x - u
          const float g2 = (x < 0.0f) ? u : tw;     // = 2*gelu(x)
          ps = fmaf(w2h[nt], g2, ps);
        }
        ps += __shfl_xor(ps, 1, 64);
        ps += __shfl_xor(ps, 2, 64);
        ps += __shfl_xor(ps, 4, 64);
        ps += __shfl_xor(ps, 8, 64);
        if (l15 == 0) {
          const int j = jt0 + m * 16 + hi4 * 4 + reg;
          const float s = ps + b2s;
          const float e2 = s / (1.0f + fabsf(s));
          orow[j] = (j == i) ? 0.0f : e2;
        }
      }
    }
  }
#undef LOADA
#undef MFMA_STEP
}

// -------------------- launch --------------------
extern "C" void kernel_launch(void* const* d_in, const int* in_sizes, int n_in,
                              void* d_out, int out_size, void* d_ws, size_t ws_size,
                              hipStream_t stream) {
  const float* latent = (const float*)d_in[0];
  const float* sng = (const float*)d_in[1];
  const float* snb = (const float*)d_in[2];
  const float* tng = (const float*)d_in[3];
  const float* tnb = (const float*)d_in[4];
  const float* sW  = (const float*)d_in[5];
  const float* sb  = (const float*)d_in[6];
  const float* tW  = (const float*)d_in[7];
  const float* tb  = (const float*)d_in[8];
  const float* W1  = (const float*)d_in[9];
  const float* b1  = (const float*)d_in[10];
  const float* W2  = (const float*)d_in[11];
  const float* b2  = (const float*)d_in[12];
  float* out = (float*)d_out;

  float* ws = (float*)d_ws;
  float* srcg  = ws;                                      // [1024][128] f32
  float* apreg = ws + 131072;                             // [1024][128] f32
  unsigned short* tgtb = (unsigned short*)(ws + 262144);  // [1024][128] u16

  hipLaunchKernelGGL(prep_kernel, dim3(256), dim3(256), 0, stream,
                     latent, sng, snb, tng, tnb, sW, sb, tW, tb, W1, b1,
                     srcg, apreg, tgtb);
  hipLaunchKernelGGL(edge_kernel, dim3(1024), dim3(256), 0, stream,
                     srcg, apreg, tgtb, W1, W2, b2, out);
}